// Round 1
// baseline (235.422 us; speedup 1.0000x reference)
//
#include <hip/hip_runtime.h>

// DynamicCache.update: out = (concat(past_key, key_states, axis=-2),
//                             concat(past_value, value_states, axis=-2))
// Shapes: past [B,H,S_PAST,D] f32, new [B,H,S_NEW,D] f32.
// d_out = k_out flat ++ v_out flat, each [B,H,S_TOT,D] f32.

constexpr unsigned B = 4, H = 32, S_PAST = 4096, S_NEW = 16, D = 128;
constexpr unsigned S_TOT = S_PAST + S_NEW;           // 4112
constexpr unsigned ROW4  = D / 4;                    // 32 float4 per row
constexpr unsigned CHUNK4 = S_TOT * ROW4;            // float4 per (b,h) chunk = 131584
constexpr unsigned HALF4 = B * H * CHUNK4;           // float4 per output tensor = 16,842,752
constexpr unsigned TOTAL4 = 2u * HALF4;              // 33,685,504 (< 2^31, 32-bit safe)

__global__ __launch_bounds__(256) void dyncache_concat_kernel(
    const float4* __restrict__ pk, const float4* __restrict__ pv,
    const float4* __restrict__ nk, const float4* __restrict__ nv,
    float4* __restrict__ out)
{
    const unsigned stride = gridDim.x * blockDim.x;
    for (unsigned i = blockIdx.x * blockDim.x + threadIdx.x; i < TOTAL4; i += stride) {
        unsigned j = i;
        const float4* past = pk;
        const float4* neu  = nk;
        if (j >= HALF4) { j -= HALF4; past = pv; neu = nv; }
        const unsigned bh  = j / CHUNK4;        // magic-mul (const divisor)
        const unsigned rem = j - bh * CHUNK4;
        const unsigned s   = rem / ROW4;
        const unsigned d4  = rem - s * ROW4;
        float4 val;
        if (s < S_PAST) {
            val = past[(bh * S_PAST + s) * ROW4 + d4];
        } else {
            val = neu[(bh * S_NEW + (s - S_PAST)) * ROW4 + d4];
        }
        out[i] = val;
    }
}

extern "C" void kernel_launch(void* const* d_in, const int* in_sizes, int n_in,
                              void* d_out, int out_size, void* d_ws, size_t ws_size,
                              hipStream_t stream) {
    const float4* pk = (const float4*)d_in[0];
    const float4* pv = (const float4*)d_in[1];
    const float4* nk = (const float4*)d_in[2];
    const float4* nv = (const float4*)d_in[3];
    float4* out = (float4*)d_out;

    // memory-bound: ~2048 blocks, grid-stride (Guideline 11)
    dyncache_concat_kernel<<<2048, 256, 0, stream>>>(pk, pv, nk, nv, out);
}

// Round 3
// 211.324 us; speedup vs baseline: 1.1140x; 1.1140x over previous
//
#include <hip/hip_runtime.h>

// DynamicCache.update: out = (concat(past_key, key_states, -2),
//                             concat(past_value, value_states, -2))
// past [B,H,S_PAST,D] f32, new [B,H,S_NEW,D] f32.
// d_out = k_out flat ++ v_out flat, each [B,H,S_TOT,D] f32.
//
// Pure streaming copy. Block-contiguous 256 KB memcpy segments:
// per-tensor past region = 2^24 float4, per-(b,h) past chunk = 2^17 float4,
// both powers of two -> tensor/chunk selection is block-uniform scalar math,
// per-thread work is 64 independent unrolled 16B copies (8 loads in flight).

typedef float f4 __attribute__((ext_vector_type(4)));   // native vec: OK for nontemporal builtins

constexpr unsigned B = 4, H = 32, S_PAST = 4096, S_NEW = 16, D = 128;
constexpr unsigned ROW4   = D / 4;              // 32 f4 per row
constexpr unsigned S_TOT  = S_PAST + S_NEW;     // 4112
constexpr unsigned CHUNK4 = S_TOT * ROW4;       // 131584 f4 per (b,h) out-chunk
constexpr unsigned HALF4  = B * H * CHUNK4;     // 16,842,752 f4 per out tensor
constexpr unsigned PASTC4 = S_PAST * ROW4;      // 131072 = 1<<17 f4 per past chunk
constexpr unsigned NEWC4  = S_NEW * ROW4;       // 512 f4 per new chunk
constexpr unsigned PAST_TOTAL4 = 2u * B * H * PASTC4;   // 1<<25
constexpr unsigned PAST_BLOCKS = 2048;
constexpr unsigned SEG4 = PAST_TOTAL4 / PAST_BLOCKS;    // 16384 f4 = 256 KB per block
constexpr unsigned NEW_BLOCKS = 2u * B * H;             // 256 (one new-region each)

__global__ __launch_bounds__(256) void dyncache_copy_kernel(
    const f4* __restrict__ pk, const f4* __restrict__ pv,
    const f4* __restrict__ nk, const f4* __restrict__ nv,
    f4* __restrict__ out)
{
    const unsigned tid = threadIdx.x;
    if (blockIdx.x < PAST_BLOCKS) {
        // ---- past copy: one contiguous 256 KB segment per block ----
        const unsigned seg = blockIdx.x * SEG4;          // flat past-f4 index
        const unsigned t   = seg >> 24;                  // which tensor (k/v)
        const unsigned loc = seg & ((1u << 24) - 1);
        const unsigned bh  = loc >> 17;                  // which (b,h) chunk
        const unsigned off = loc & (PASTC4 - 1);         // offset within chunk
        const f4* __restrict__ src =
            (t ? pv : pk) + ((size_t)bh << 17) + off;
        f4* __restrict__ dst =
            out + (size_t)t * HALF4 + (size_t)bh * CHUNK4 + off;
        #pragma unroll 8
        for (unsigned k = 0; k < SEG4 / 256u; ++k) {
            const unsigned i = k * 256u + tid;
            __builtin_nontemporal_store(__builtin_nontemporal_load(src + i), dst + i);
        }
    } else {
        // ---- new-token tails: one 8 KB region per block ----
        const unsigned blk = blockIdx.x - PAST_BLOCKS;   // 0..255
        const unsigned t   = blk >> 7;
        const unsigned bh  = blk & (B * H - 1);
        const f4* __restrict__ src = (t ? nv : nk) + (size_t)bh * NEWC4;
        f4* __restrict__ dst =
            out + (size_t)t * HALF4 + (size_t)bh * CHUNK4 + PASTC4;
        #pragma unroll
        for (unsigned k = 0; k < NEWC4 / 256u; ++k) {
            const unsigned i = k * 256u + tid;
            __builtin_nontemporal_store(__builtin_nontemporal_load(src + i), dst + i);
        }
    }
}

extern "C" void kernel_launch(void* const* d_in, const int* in_sizes, int n_in,
                              void* d_out, int out_size, void* d_ws, size_t ws_size,
                              hipStream_t stream) {
    const f4* pk = (const f4*)d_in[0];
    const f4* pv = (const f4*)d_in[1];
    const f4* nk = (const f4*)d_in[2];
    const f4* nv = (const f4*)d_in[3];
    f4* out = (f4*)d_out;

    dyncache_copy_kernel<<<PAST_BLOCKS + NEW_BLOCKS, 256, 0, stream>>>(
        pk, pv, nk, nv, out);
}

// Round 4
// 190.514 us; speedup vs baseline: 1.2357x; 1.1092x over previous
//
#include <hip/hip_runtime.h>

// DynamicCache.update concat copy — software-pipelined streaming memcpy.
// past [B,H,S_PAST,D] f32, new [B,H,S_NEW,D] f32.
// d_out = k_out ++ v_out, each [B,H,S_TOT,D] f32.
//
// Latency-limited copy fix: double-buffered groups of 12 float4 per thread so
// 12-24 loads stay in flight continuously (load g+1 issues BEFORE store g).
// Grid = 1024 blocks exactly (4/CU, all resident); new-token tails folded
// into blocks 0..255.

typedef float f4 __attribute__((ext_vector_type(4)));

constexpr unsigned B = 4, H = 32, S_PAST = 4096, S_NEW = 16, D = 128;
constexpr unsigned ROW4   = D / 4;              // 32 f4 per row
constexpr unsigned S_TOT  = S_PAST + S_NEW;     // 4112
constexpr unsigned CHUNK4 = S_TOT * ROW4;       // 131584 f4 per (b,h) out-chunk
constexpr unsigned HALF4  = B * H * CHUNK4;     // f4 per out tensor
constexpr unsigned PASTC4 = S_PAST * ROW4;      // 1<<17 f4 per past chunk
constexpr unsigned NEWC4  = S_NEW * ROW4;       // 512 f4 per new chunk
constexpr unsigned PAST_TOTAL4 = 2u * B * H * PASTC4;   // 1<<25
constexpr unsigned BLOCKS = 1024;
constexpr unsigned SEG4  = PAST_TOTAL4 / BLOCKS;        // 32768 f4 = 512 KB
constexpr unsigned ITERS = SEG4 / 256u;                 // 128 f4 per thread
constexpr unsigned GRP   = 12;
constexpr unsigned NGRP  = ITERS / GRP;                 // 10 full groups
constexpr unsigned REM   = ITERS - NGRP * GRP;          // 8 remainder

__global__ __launch_bounds__(256, 4) void dyncache_copy_kernel(
    const f4* __restrict__ pk, const f4* __restrict__ pv,
    const f4* __restrict__ nk, const f4* __restrict__ nv,
    f4* __restrict__ out)
{
    const unsigned tid = threadIdx.x;

    // ---- new-token tails, folded into blocks 0..255 (2 f4/thread) ----
    if (blockIdx.x < 2u * B * H) {
        const unsigned t  = blockIdx.x >> 7;          // 0..127 -> k, 128..255 -> v
        const unsigned bh = blockIdx.x & (B * H - 1);
        const f4* __restrict__ s = (t ? nv : nk) + (size_t)bh * NEWC4;
        f4* __restrict__ d =
            out + (size_t)t * HALF4 + (size_t)bh * CHUNK4 + PASTC4;
        #pragma unroll
        for (unsigned k = 0; k < NEWC4 / 256u; ++k)
            __builtin_nontemporal_store(
                __builtin_nontemporal_load(s + k * 256u + tid), d + k * 256u + tid);
    }

    // ---- main past copy: one contiguous 512 KB segment per block ----
    const unsigned seg = blockIdx.x * SEG4;           // flat past-f4 index
    const unsigned t   = seg >> 24;                   // tensor (k/v)
    const unsigned loc = seg & ((1u << 24) - 1);
    const unsigned bh  = loc >> 17;                   // (b,h) chunk
    const unsigned off = loc & (PASTC4 - 1);          // offset within chunk
    const f4* __restrict__ src =
        (t ? pv : pk) + ((size_t)bh << 17) + off + tid;
    f4* __restrict__ dst =
        out + (size_t)t * HALF4 + (size_t)bh * CHUNK4 + off + tid;

    f4 a[GRP], b[GRP];

    // prologue: load group 0 into A
    #pragma unroll
    for (unsigned j = 0; j < GRP; ++j)
        a[j] = __builtin_nontemporal_load(src + (0u * GRP + j) * 256u);

    // steady state: groups 1..9 — load next buffer BEFORE storing previous.
    // 5 fully-unrolled pairs would cover g=1..10; we have g=1..9, so 4 pairs
    // (g=1..8) + one odd step (g=9). All buffer indices compile-time static.
    #pragma unroll
    for (unsigned p = 0; p < 4; ++p) {
        const unsigned g1 = 2u * p + 1u;              // load B, store A(g1-1)
        #pragma unroll
        for (unsigned j = 0; j < GRP; ++j)
            b[j] = __builtin_nontemporal_load(src + (g1 * GRP + j) * 256u);
        #pragma unroll
        for (unsigned j = 0; j < GRP; ++j)
            __builtin_nontemporal_store(a[j], dst + ((g1 - 1u) * GRP + j) * 256u);
        const unsigned g2 = 2u * p + 2u;              // load A, store B(g2-1)
        #pragma unroll
        for (unsigned j = 0; j < GRP; ++j)
            a[j] = __builtin_nontemporal_load(src + (g2 * GRP + j) * 256u);
        #pragma unroll
        for (unsigned j = 0; j < GRP; ++j)
            __builtin_nontemporal_store(b[j], dst + ((g2 - 1u) * GRP + j) * 256u);
    }
    // g = 9: load B, store A(g8)
    #pragma unroll
    for (unsigned j = 0; j < GRP; ++j)
        b[j] = __builtin_nontemporal_load(src + (9u * GRP + j) * 256u);
    #pragma unroll
    for (unsigned j = 0; j < GRP; ++j)
        __builtin_nontemporal_store(a[j], dst + (8u * GRP + j) * 256u);
    // drain: store B(g9)
    #pragma unroll
    for (unsigned j = 0; j < GRP; ++j)
        __builtin_nontemporal_store(b[j], dst + (9u * GRP + j) * 256u);

    // remainder: 8 f4 (reuses A regs)
    #pragma unroll
    for (unsigned j = 0; j < REM; ++j)
        a[j] = __builtin_nontemporal_load(src + (NGRP * GRP + j) * 256u);
    #pragma unroll
    for (unsigned j = 0; j < REM; ++j)
        __builtin_nontemporal_store(a[j], dst + (NGRP * GRP + j) * 256u);
}

extern "C" void kernel_launch(void* const* d_in, const int* in_sizes, int n_in,
                              void* d_out, int out_size, void* d_ws, size_t ws_size,
                              hipStream_t stream) {
    const f4* pk = (const f4*)d_in[0];
    const f4* pv = (const f4*)d_in[1];
    const f4* nk = (const f4*)d_in[2];
    const f4* nv = (const f4*)d_in[3];
    f4* out = (f4*)d_out;

    dyncache_copy_kernel<<<BLOCKS, 256, 0, stream>>>(pk, pv, nk, nv, out);
}